// Round 1
// baseline (45.218 us; speedup 1.0000x reference)
//
#include <hip/hip_runtime.h>
#include <hip/hip_bf16.h>

// Problem constants
// B=64, C=4, H=256, W=256; SCALES=(8,16,32); windows=(0,250,500,750,1000)
// KEY_INT = 0x5D1CE5 = 6102245
// base_core = (KEY_INT * 2654435761) % 10007  (product ~1.62e19 fits in u64)
static constexpr unsigned long long KEY_MUL =
    (6102245ULL * 2654435761ULL) % 10007ULL;
static constexpr int HASH_MOD = 10007;
static constexpr float TWO_PI = 6.2831853f;

// ---------------------------------------------------------------------------
// Kernel 1: pool latent -> 8x8-patch sums [32x32] in ws_sum.
// grid = (32 plane-chunks, 32 patch-rows), block = 256 threads.
// Each block: 8 planes x 8 rows x 256 cols of one patch-row, float4 loads.
// ---------------------------------------------------------------------------
__global__ __launch_bounds__(256) void pool_kernel(
    const float* __restrict__ latent, float* __restrict__ ws_sum) {
  const int pr  = blockIdx.y;   // patch row 0..31
  const int pc0 = blockIdx.x;   // plane chunk 0..31 (8 planes each)
  const int t   = threadIdx.x;  // 0..255
  const int cl  = t & 63;       // float4 column within row (0..63)
  const int rg  = t >> 6;       // wave index = row group 0..3

  float acc = 0.0f;
  const float4* base = reinterpret_cast<const float4*>(latent);
  for (int pl = 0; pl < 8; ++pl) {
    const size_t plane = (size_t)(pc0 * 8 + pl);
    const float4* prow = base + plane * 16384;  // 256*256/4 float4 per plane
#pragma unroll
    for (int rr = 0; rr < 2; ++rr) {
      const int r = pr * 8 + rg + rr * 4;       // rows pr*8 .. pr*8+7
      float4 v = prow[r * 64 + cl];
      acc += v.x + v.y + v.z + v.w;
    }
  }
  // lanes 2c and 2c+1 cover the same 8-wide patch column
  acc += __shfl_xor(acc, 1, 64);

  __shared__ float lds[4][32];
  if ((cl & 1) == 0) lds[rg][cl >> 1] = acc;
  __syncthreads();
  if (t < 32) {
    float s = lds[0][t] + lds[1][t] + lds[2][t] + lds[3][t];
    atomicAdd(&ws_sum[pr * 32 + t], s);
  }
}

// ---------------------------------------------------------------------------
// Kernel 2: single tiny block. Reads timestep, builds g*strength tables:
// g8[1024], g16[256], g32[64] appended contiguously at gtab.
// ---------------------------------------------------------------------------
__global__ __launch_bounds__(1024) void gmap_kernel(
    const float* __restrict__ ws_sum, const int* __restrict__ tstep,
    float* __restrict__ gtab) {
  const int t = threadIdx.x;  // 0..1023
  const int ts = *tstep;

  // bucket = searchsorted(windows, ts, side='right') - 1 = count(w <= ts) - 1
  int bucket = -1;
  const int wins[5] = {0, 250, 500, 750, 1000};
#pragma unroll
  for (int k = 0; k < 5; ++k) bucket += (ts >= wins[k]) ? 1 : 0;

  const double expo = exp(-(double)ts / 1000.0);
  const float phase_k = (float)(6.2831853 / 10007.0);

  // ---- scale 8: 32x32 entries ----
  {
    const int p = 8;
    const int i = t >> 5, j = t & 31;
    const long long b =
        ((long long)KEY_MUL + p * 97 + bucket * 139 + 10 * HASH_MOD) % HASH_MOD;
    const int h = (int)((b + (long long)i * (p * 131) + (long long)j * (p * 137)) % HASH_MOD);
    const float pooled = ws_sum[t] * (1.0f / 16384.0f);  // B*C*64
    const float strength = (float)(0.05 / sqrt((double)p) * expo);
    gtab[t] = cosf(pooled * 3.0f + (float)h * phase_k) * strength;
  }
  // ---- scale 16: 16x16 entries (aggregate 2x2 of 8-sums) ----
  if (t < 256) {
    const int p = 16;
    const int i = t >> 4, j = t & 15;
    const long long b =
        ((long long)KEY_MUL + p * 97 + bucket * 139 + 10 * HASH_MOD) % HASH_MOD;
    const int h = (int)((b + (long long)i * (p * 131) + (long long)j * (p * 137)) % HASH_MOD);
    const float s =
        ws_sum[(2 * i) * 32 + 2 * j] + ws_sum[(2 * i) * 32 + 2 * j + 1] +
        ws_sum[(2 * i + 1) * 32 + 2 * j] + ws_sum[(2 * i + 1) * 32 + 2 * j + 1];
    const float pooled = s * (1.0f / 65536.0f);  // B*C*256
    const float strength = (float)(0.05 / sqrt((double)p) * expo);
    gtab[1024 + t] = cosf(pooled * 3.0f + (float)h * phase_k) * strength;
  }
  // ---- scale 32: 8x8 entries (aggregate 4x4 of 8-sums) ----
  if (t < 64) {
    const int p = 32;
    const int i = t >> 3, j = t & 7;
    const long long b =
        ((long long)KEY_MUL + p * 97 + bucket * 139 + 10 * HASH_MOD) % HASH_MOD;
    const int h = (int)((b + (long long)i * (p * 131) + (long long)j * (p * 137)) % HASH_MOD);
    float s = 0.0f;
    for (int di = 0; di < 4; ++di)
      for (int dj = 0; dj < 4; ++dj)
        s += ws_sum[(4 * i + di) * 32 + 4 * j + dj];
    const float pooled = s * (1.0f / 262144.0f);  // B*C*1024
    const float strength = (float)(0.05 / sqrt((double)p) * expo);
    gtab[1280 + t] = cosf(pooled * 3.0f + (float)h * phase_k) * strength;
  }
}

// ---------------------------------------------------------------------------
// Kernel 3: out = noise + bias(h,w). float4 grid-stride; bias tables in LDS.
// An aligned float4 (4 consecutive w) never crosses an 8-wide patch column,
// so one bias scalar per float4.
// ---------------------------------------------------------------------------
__global__ __launch_bounds__(256) void add_kernel(
    const float* __restrict__ noise, const float* __restrict__ gtab,
    float* __restrict__ out) {
  __shared__ float g8[1024];
  __shared__ float g16[256];
  __shared__ float g32[64];
  for (int i = threadIdx.x; i < 1344; i += blockDim.x) {
    float v = gtab[i];
    if (i < 1024) g8[i] = v;
    else if (i < 1280) g16[i - 1024] = v;
    else g32[i - 1280] = v;
  }
  __syncthreads();

  const float4* __restrict__ n4 = reinterpret_cast<const float4*>(noise);
  float4* __restrict__ o4 = reinterpret_cast<float4*>(out);
  const int total4 = 64 * 4 * 256 * 256 / 4;  // 4194304
  const int stride = gridDim.x * blockDim.x;
  for (int f = blockIdx.x * blockDim.x + threadIdx.x; f < total4; f += stride) {
    const int fp = f & 16383;  // float4 index within one [256,256] plane
    const int h = fp >> 6;     // row
    const int wq = fp & 63;    // float4 column; w = wq*4
    const float bias = g8[(h >> 3) * 32 + (wq >> 1)] +
                       g16[(h >> 4) * 16 + (wq >> 2)] +
                       g32[(h >> 5) * 8 + (wq >> 3)];
    float4 v = n4[f];
    v.x += bias; v.y += bias; v.z += bias; v.w += bias;
    o4[f] = v;
  }
}

extern "C" void kernel_launch(void* const* d_in, const int* in_sizes, int n_in,
                              void* d_out, int out_size, void* d_ws, size_t ws_size,
                              hipStream_t stream) {
  const float* noise  = (const float*)d_in[0];
  const float* latent = (const float*)d_in[1];
  const int*   tstep  = (const int*)d_in[2];
  float* out = (float*)d_out;
  float* ws  = (float*)d_ws;

  float* ws_sum = ws;         // 1024 floats: 8x8-patch sums
  float* gtab   = ws + 1024;  // 1344 floats: g8 | g16 | g32

  hipMemsetAsync(ws_sum, 0, 1024 * sizeof(float), stream);
  pool_kernel<<<dim3(32, 32), 256, 0, stream>>>(latent, ws_sum);
  gmap_kernel<<<1, 1024, 0, stream>>>(ws_sum, tstep, gtab);
  add_kernel<<<2048, 256, 0, stream>>>(noise, gtab, out);
}

// Round 2
// 43.016 us; speedup vs baseline: 1.0512x; 1.0512x over previous
//
#include <hip/hip_runtime.h>
#include <hip/hip_bf16.h>

// Problem constants
// B=64, C=4, H=256, W=256; SCALES=(8,16,32); windows=(0,250,500,750,1000)
// KEY_INT = 0x5D1CE5 = 6102245
// base_core = (KEY_INT * 2654435761) % 10007  (product ~1.62e19 fits in u64)
static constexpr unsigned long long KEY_MUL =
    (6102245ULL * 2654435761ULL) % 10007ULL;
static constexpr int HASH_MOD = 10007;

// ---------------------------------------------------------------------------
// Kernel 1: pool latent -> per-chunk partial sums of 8x8 patches.
// grid = (NCH plane-chunks, 32 patch-rows), block = 256.
// Block (ch, pr): sums planes [ch*PPC, (ch+1)*PPC) over patch-row pr,
// writes 32 partials to ws_partial[(pr*32+pc)*NCH + ch].
// ---------------------------------------------------------------------------
template <int NCH>
__global__ __launch_bounds__(256) void pool_kernel(
    const float* __restrict__ latent, float* __restrict__ ws_partial) {
  constexpr int PPC = 256 / NCH;  // planes per chunk
  const int pr = blockIdx.y;      // patch row 0..31
  const int ch = blockIdx.x;      // chunk
  const int t  = threadIdx.x;
  const int cl = t & 63;          // float4 column (0..63)
  const int rg = t >> 6;          // row group 0..3

  float acc = 0.0f;
  const float4* base = reinterpret_cast<const float4*>(latent);
#pragma unroll 8
  for (int pl = 0; pl < PPC; ++pl) {
    const float4* prow = base + (size_t)(ch * PPC + pl) * 16384;
#pragma unroll
    for (int rr = 0; rr < 2; ++rr) {
      float4 v = prow[(pr * 8 + rg + rr * 4) * 64 + cl];
      acc += (v.x + v.y) + (v.z + v.w);
    }
  }
  // lanes 2c, 2c+1 cover the same 8-wide patch column
  acc += __shfl_xor(acc, 1, 64);

  __shared__ float lds[4][32];
  if ((cl & 1) == 0) lds[rg][cl >> 1] = acc;
  __syncthreads();
  if (t < 32) {
    float s = (lds[0][t] + lds[1][t]) + (lds[2][t] + lds[3][t]);
    ws_partial[(pr * 32 + t) * NCH + ch] = s;
  }
}

// ---------------------------------------------------------------------------
// Kernel 2: single block. Reduce partials -> s8 (LDS), then build
// g*strength tables: g8[1024] | g16[256] | g32[64] at gtab.
// ---------------------------------------------------------------------------
template <int NCH>
__global__ __launch_bounds__(1024) void gmap_kernel(
    const float* __restrict__ ws_partial, const int* __restrict__ tstep,
    float* __restrict__ gtab) {
  __shared__ float s8[1024];
  const int t = threadIdx.x;  // 0..1023 = patch linear index for scale 8
  {
    float s = 0.0f;
    if constexpr (NCH >= 4) {
      const float4* p4 = reinterpret_cast<const float4*>(ws_partial) + t * (NCH / 4);
#pragma unroll
      for (int c = 0; c < NCH / 4; ++c) {
        float4 v = p4[c];
        s += (v.x + v.y) + (v.z + v.w);
      }
    } else {
#pragma unroll
      for (int c = 0; c < NCH; ++c) s += ws_partial[t * NCH + c];
    }
    s8[t] = s;
  }
  __syncthreads();

  const int ts = *tstep;
  // bucket = searchsorted(windows, ts, 'right') - 1 = count(w <= ts) - 1
  int bucket = -1;
  const int wins[5] = {0, 250, 500, 750, 1000};
#pragma unroll
  for (int k = 0; k < 5; ++k) bucket += (ts >= wins[k]) ? 1 : 0;

  const double expo = exp(-(double)ts / 1000.0);
  const float phase_k = (float)(6.2831853 / 10007.0);

  // ---- scale 8: 32x32 ----
  {
    const int p = 8, i = t >> 5, j = t & 31;
    const long long b =
        ((long long)KEY_MUL + p * 97 + bucket * 139 + 10 * HASH_MOD) % HASH_MOD;
    const int h = (int)((b + (long long)i * (p * 131) + (long long)j * (p * 137)) % HASH_MOD);
    const float pooled = s8[t] * (1.0f / 16384.0f);  // /(B*C*64)
    const float strength = (float)(0.05 / sqrt((double)p) * expo);
    gtab[t] = cosf(pooled * 3.0f + (float)h * phase_k) * strength;
  }
  // ---- scale 16: 16x16 (2x2 aggregate of s8) ----
  if (t < 256) {
    const int p = 16, i = t >> 4, j = t & 15;
    const long long b =
        ((long long)KEY_MUL + p * 97 + bucket * 139 + 10 * HASH_MOD) % HASH_MOD;
    const int h = (int)((b + (long long)i * (p * 131) + (long long)j * (p * 137)) % HASH_MOD);
    const float s = (s8[(2 * i) * 32 + 2 * j] + s8[(2 * i) * 32 + 2 * j + 1]) +
                    (s8[(2 * i + 1) * 32 + 2 * j] + s8[(2 * i + 1) * 32 + 2 * j + 1]);
    const float pooled = s * (1.0f / 65536.0f);  // /(B*C*256)
    const float strength = (float)(0.05 / sqrt((double)p) * expo);
    gtab[1024 + t] = cosf(pooled * 3.0f + (float)h * phase_k) * strength;
  }
  // ---- scale 32: 8x8 (4x4 aggregate of s8) ----
  if (t < 64) {
    const int p = 32, i = t >> 3, j = t & 7;
    const long long b =
        ((long long)KEY_MUL + p * 97 + bucket * 139 + 10 * HASH_MOD) % HASH_MOD;
    const int h = (int)((b + (long long)i * (p * 131) + (long long)j * (p * 137)) % HASH_MOD);
    float s = 0.0f;
#pragma unroll
    for (int di = 0; di < 4; ++di)
#pragma unroll
      for (int dj = 0; dj < 4; ++dj) s += s8[(4 * i + di) * 32 + 4 * j + dj];
    const float pooled = s * (1.0f / 262144.0f);  // /(B*C*1024)
    const float strength = (float)(0.05 / sqrt((double)p) * expo);
    gtab[1280 + t] = cosf(pooled * 3.0f + (float)h * phase_k) * strength;
  }
}

// ---------------------------------------------------------------------------
// Kernel 3: out = noise + bias(h,w). 2048 blocks x 256 threads x 8 float4,
// fully unrolled: 8 loads in flight per thread (ILP), then bias+store.
// Block b: plane b>>3, 32-row slab o=b&7. Thread t, step k:
//   f = b*2048 + k*256 + t ; h = o*32 + 4k + (t>>6) ; wq = t&63.
// ---------------------------------------------------------------------------
__global__ __launch_bounds__(256) void add_kernel(
    const float* __restrict__ noise, const float* __restrict__ gtab,
    float* __restrict__ out) {
  __shared__ float g8[1024];
  __shared__ float g16[256];
  __shared__ float g32[64];
  const int t = threadIdx.x;
  for (int i = t; i < 1344; i += 256) {
    float v = gtab[i];
    if (i < 1024) g8[i] = v;
    else if (i < 1280) g16[i - 1024] = v;
    else g32[i - 1280] = v;
  }
  __syncthreads();

  const int b = blockIdx.x;  // 0..2047
  const size_t f_base = (size_t)b * 2048 + t;
  const int o = b & 7;
  const int c8 = (t & 63) >> 1, c16 = (t & 63) >> 2, c32 = (t & 63) >> 3;
  const int h0 = o * 32 + (t >> 6);

  const float4* __restrict__ n4 = reinterpret_cast<const float4*>(noise);
  float4* __restrict__ o4 = reinterpret_cast<float4*>(out);

  float4 v[8];
#pragma unroll
  for (int k = 0; k < 8; ++k) v[k] = n4[f_base + (size_t)k * 256];

  float bias[8];
#pragma unroll
  for (int k = 0; k < 8; ++k) {
    const int h = h0 + k * 4;
    bias[k] = g8[(h >> 3) * 32 + c8] + g16[(h >> 4) * 16 + c16] +
              g32[(h >> 5) * 8 + c32];
  }

#pragma unroll
  for (int k = 0; k < 8; ++k) {
    float4 w = v[k];
    w.x += bias[k]; w.y += bias[k]; w.z += bias[k]; w.w += bias[k];
    o4[f_base + (size_t)k * 256] = w;
  }
}

extern "C" void kernel_launch(void* const* d_in, const int* in_sizes, int n_in,
                              void* d_out, int out_size, void* d_ws, size_t ws_size,
                              hipStream_t stream) {
  const float* noise  = (const float*)d_in[0];
  const float* latent = (const float*)d_in[1];
  const int*   tstep  = (const int*)d_in[2];
  float* out = (float*)d_out;
  float* ws  = (float*)d_ws;

  const size_t need32 = (size_t)(1024 * 32 + 1344) * sizeof(float);  // ~137 KB
  const size_t need8  = (size_t)(1024 * 8 + 1344) * sizeof(float);   // ~38 KB

  float* gtab;
  if (ws_size >= need32) {
    float* part = ws; gtab = ws + 1024 * 32;
    pool_kernel<32><<<dim3(32, 32), 256, 0, stream>>>(latent, part);
    gmap_kernel<32><<<1, 1024, 0, stream>>>(part, tstep, gtab);
  } else if (ws_size >= need8) {
    float* part = ws; gtab = ws + 1024 * 8;
    pool_kernel<8><<<dim3(8, 32), 256, 0, stream>>>(latent, part);
    gmap_kernel<8><<<1, 1024, 0, stream>>>(part, tstep, gtab);
  } else {
    float* part = ws; gtab = ws + 1024;
    pool_kernel<1><<<dim3(1, 32), 256, 0, stream>>>(latent, part);
    gmap_kernel<1><<<1, 1024, 0, stream>>>(part, tstep, gtab);
  }
  add_kernel<<<2048, 256, 0, stream>>>(noise, gtab, out);
}